// Round 4
// baseline (168.865 us; speedup 1.0000x reference)
//
#include <hip/hip_runtime.h>
#include <cmath>

#define NN 64
#define CC 96
#define TT 128
#define VV 25
#define SS 3

/* k1 tile (round-2 proven) */
#define TB 4
#define NTB (TT/TB)          /* 32 */
#define ROWS (TB*VV)         /* 100 */
#define XTROWS 112

/* k3 tile (new: TB=2 for occupancy) */
#define TB3 2
#define NTB3 (TT/TB3)        /* 64 */
#define ROWS3 (TB3*VV)       /* 50 */
#define XTROWS3 64

#define XTP 104              /* xT row pad (bf16 elems), 208B rows */
#define QKP 200              /* qk row pad, 400B rows */
#define VALP 40              /* val row pad, 80B rows */
#define YLP 104              /* y row pad, 208B rows */

typedef __attribute__((ext_vector_type(8))) __bf16 bf16x8;
typedef __attribute__((ext_vector_type(4))) float f32x4;

#define MFMA16(a,b,c) __builtin_amdgcn_mfma_f32_16x16x32_bf16((a),(b),(c),0,0,0)

__constant__ int JP[25] = {0,0,1,1,2,2,2,3,4,4,4,5,6,6,7,7,8,8,9,9,0,3,3,5,5};
__constant__ int JB[25] = {4,4,4,4,0,0,0,0,1,1,1,1,2,2,2,2,3,3,3,3,4,0,0,1,1};

__device__ inline unsigned short f2b(float f) {
  unsigned int u = __float_as_uint(f);
  u += 0x7fffu + ((u >> 16) & 1u);
  return (unsigned short)(u >> 16);
}
__device__ inline float b2f(unsigned short h) {
  return __uint_as_float(((unsigned int)h) << 16);
}
__device__ inline bf16x8 ldbf8(const unsigned short* p) {
  union { uint4 u; bf16x8 b; } z;
  z.u = *(const uint4*)p;
  return z.b;
}
__device__ inline f32x4 fz() {
  f32x4 z; z[0] = 0.f; z[1] = 0.f; z[2] = 0.f; z[3] = 0.f; return z;
}

// ---------------------------------------------------------------------------
// k0: weights -> bf16 in ws; BN scale/shift precompute
// ---------------------------------------------------------------------------
__global__ __launch_bounds__(256) void k0(
    const float* __restrict__ w_in, const float* __restrict__ w_ff,
    const float* __restrict__ b_ff, const float* __restrict__ gam,
    const float* __restrict__ bet, const float* __restrict__ mea,
    const float* __restrict__ var,
    unsigned short* __restrict__ wbin, unsigned short* __restrict__ wbff,
    float* __restrict__ scsh)
{
  int i = blockIdx.x * 256 + threadIdx.x;
  if (i < 288 * 96) wbin[i] = f2b(w_in[i]);
  if (i < 96 * 96)  wbff[i] = f2b(w_ff[i]);
  if (i < 96) {
    float sc = gam[i] * rsqrtf(var[i] + 1e-5f);
    scsh[i]      = sc;
    scsh[96 + i] = (b_ff[i] - mea[i]) * sc + bet[i];
  }
}

// ---------------------------------------------------------------------------
// k1: per (n, tb): QK GEMM (MFMA) -> Gram partials   [round-2 proven version]
// ---------------------------------------------------------------------------
__global__ __launch_bounds__(256, 2) void k1(
    const float* __restrict__ x, const unsigned short* __restrict__ wbin,
    const float* __restrict__ b_in, float* __restrict__ partG)
{
  __shared__ unsigned short xT[XTROWS * XTP];   // [i=dt*25+v][c] bf16
  __shared__ unsigned short qk[XTROWS * QKP];   // [i=dt*25+v][o 0..191] bf16
  __shared__ float bL[192];

  const int tid  = threadIdx.x;
  const int wid  = tid >> 6, lane = tid & 63;
  const int lrow = lane & 15;
  const int lk8  = (lane >> 4) << 3;
  const int ldr4 = (lane >> 4) << 2;
  const int tb = blockIdx.x & (NTB - 1);
  const int n  = blockIdx.x >> 5;
  const int t0 = tb * TB;

  // stage xT[i][c]: contiguous LDS writes (conflict-free), scalar global reads
  const float* xb = x + (size_t)n * CC * TT * VV + (size_t)t0 * VV;
  for (int e = tid; e < CC * ROWS; e += 256) {
    int i = e / CC, c = e - i * CC;
    xT[i * XTP + c] = f2b(xb[(size_t)c * TT * VV + i]);
  }
  if (tid < 192) bL[tid] = b_in[tid];
  __syncthreads();

  // QK GEMM: D[o=0..191][col=0..111] ; wave handles mf = 3*wid..3*wid+2
  f32x4 acc[3][7];
  #pragma unroll
  for (int i = 0; i < 3; ++i)
    #pragma unroll
    for (int nf = 0; nf < 7; ++nf) acc[i][nf] = fz();

  #pragma unroll
  for (int ks = 0; ks < 3; ++ks) {
    bf16x8 a[3];
    #pragma unroll
    for (int i = 0; i < 3; ++i)
      a[i] = ldbf8(&wbin[((wid * 3 + i) * 16 + lrow) * 96 + ks * 32 + lk8]);
    #pragma unroll
    for (int nf = 0; nf < 7; ++nf) {
      bf16x8 b = ldbf8(&xT[(nf * 16 + lrow) * XTP + ks * 32 + lk8]);
      #pragma unroll
      for (int i = 0; i < 3; ++i)
        acc[i][nf] = MFMA16(a[i], b, acc[i][nf]);
    }
  }
  // bias + bf16 + store to qk[col][o]
  #pragma unroll
  for (int i = 0; i < 3; ++i) {
    int ob = (wid * 3 + i) * 16 + ldr4;
    float4 bb = *(const float4*)&bL[ob];
    #pragma unroll
    for (int nf = 0; nf < 7; ++nf) {
      int col = nf * 16 + lrow;
      ushort4 h;
      h.x = f2b(acc[i][nf][0] + bb.x);
      h.y = f2b(acc[i][nf][1] + bb.y);
      h.z = f2b(acc[i][nf][2] + bb.z);
      h.w = f2b(acc[i][nf][3] + bb.w);
      *(ushort4*)&qk[col * QKP + ob] = h;
    }
  }
  __syncthreads();

  // Gram: waves 0..2, s = wid
  if (wid < 3) {
    const int s = wid;
    f32x4 g[2][2];
    g[0][0] = fz(); g[0][1] = fz(); g[1][0] = fz(); g[1][1] = fz();
    #pragma unroll
    for (int dt = 0; dt < TB; ++dt) {
      int r0 = dt * VV;
      bf16x8 a0 = ldbf8(&qk[(r0 + lrow) * QKP + s * 32 + lk8]);
      bf16x8 a1 = ldbf8(&qk[(r0 + 16 + lrow) * QKP + s * 32 + lk8]);
      bf16x8 b0 = ldbf8(&qk[(r0 + lrow) * QKP + 96 + s * 32 + lk8]);
      bf16x8 b1 = ldbf8(&qk[(r0 + 16 + lrow) * QKP + 96 + s * 32 + lk8]);
      g[0][0] = MFMA16(a0, b0, g[0][0]);
      g[0][1] = MFMA16(a0, b1, g[0][1]);
      g[1][0] = MFMA16(a1, b0, g[1][0]);
      g[1][1] = MFMA16(a1, b1, g[1][1]);
    }
    float* pg = partG + ((size_t)(n * SS + s) * NTB + tb) * (VV * VV);
    #pragma unroll
    for (int mi = 0; mi < 2; ++mi)
      #pragma unroll
      for (int ni = 0; ni < 2; ++ni)
        #pragma unroll
        for (int r = 0; r < 4; ++r) {
          int u = mi * 16 + ldr4 + r, v = ni * 16 + lrow;
          if (u < VV && v < VV) pg[u * VV + v] = g[mi][ni][r];
        }
  }
}

// ---------------------------------------------------------------------------
// k2: reduce partials, tanh + positional gathers -> att bf16 [ns][32][32]
// ---------------------------------------------------------------------------
__global__ __launch_bounds__(256) void k2(
    const float* __restrict__ partG, const float* __restrict__ p_att,
    const float* __restrict__ b_att, unsigned short* __restrict__ att)
{
  const int ns = blockIdx.x;
  for (int e = threadIdx.x; e < 1024; e += 256) {
    int u = e >> 5, v = e & 31;
    float a = 0.f;
    if (u < VV && v < VV) {
      float g = 0.f;
      const float* pg = partG + (size_t)ns * NTB * (VV * VV) + u * VV + v;
      for (int tb = 0; tb < NTB; ++tb) g += pg[tb * VV * VV];
      a = tanhf(g * (1.0f / 4096.0f))
        + p_att[(size_t)ns * 100 + JP[u] * 10 + JP[v]]
        + b_att[(size_t)ns * 25  + JB[u] * 5  + JB[v]];
    }
    att[(size_t)ns * 1024 + e] = f2b(a);
  }
}

// ---------------------------------------------------------------------------
// k3: per (n, tb2): VAL GEMM -> PV -> FF GEMM -> BN + residual + leaky
// TB=2 tile: LDS = 13312 + 15360 = 28672 B -> 5 blocks/CU by LDS,
// 16 waves/CU at VGPR<=128. One col-frag per wave in every phase.
// ---------------------------------------------------------------------------
__global__ __launch_bounds__(256, 2) void k3(
    const float* __restrict__ x, const unsigned short* __restrict__ wbin,
    const unsigned short* __restrict__ wbff,
    const float* __restrict__ b_in, const float* __restrict__ scsh,
    const unsigned short* __restrict__ att, float* __restrict__ out)
{
  __shared__ unsigned short xT[XTROWS3 * XTP];  // 13312 B  [i=dt*25+v][c]
  __shared__ unsigned short val[192 * VALP];    // 15360 B  [dt*96+c][v]; yL overlays

  const int tid  = threadIdx.x;
  const int wid  = tid >> 6, lane = tid & 63;
  const int lrow = lane & 15;
  const int lk8  = (lane >> 4) << 3;
  const int ldr4 = (lane >> 4) << 2;
  const int tb = blockIdx.x & (NTB3 - 1);
  const int n  = blockIdx.x >> 6;
  const int t0 = tb * TB3;

  // stage xT[i][c]: contiguous LDS writes, scalar global reads (L3-hot)
  const float* xb = x + (size_t)n * CC * TT * VV + (size_t)t0 * VV;
  for (int e = tid; e < CC * ROWS3; e += 256) {
    int i = e / CC, c = e - i * CC;
    xT[i * XTP + c] = f2b(xb[(size_t)c * TT * VV + i]);
  }
  // zero val K-pad cols 24..31 (col 24 rewritten by VAL; 25..31 stay 0)
  {
    uint4 z; z.x = 0u; z.y = 0u; z.z = 0u; z.w = 0u;
    for (int e = tid; e < 192; e += 256)
      *(uint4*)&val[e * VALP + 24] = z;
  }
  __syncthreads();

  // VAL GEMM: D[c=0..95][col=0..63]; wave handles nf = wid
  {
    f32x4 acc[6];
    #pragma unroll
    for (int mf = 0; mf < 6; ++mf) acc[mf] = fz();
    #pragma unroll
    for (int ks = 0; ks < 3; ++ks) {
      bf16x8 b = ldbf8(&xT[(wid * 16 + lrow) * XTP + ks * 32 + lk8]);
      #pragma unroll
      for (int mf = 0; mf < 6; ++mf) {
        bf16x8 a = ldbf8(&wbin[(192 + mf * 16 + lrow) * 96 + ks * 32 + lk8]);
        acc[mf] = MFMA16(a, b, acc[mf]);
      }
    }
    int col = wid * 16 + lrow;
    if (col < ROWS3) {
      int dt = col / VV, v = col - dt * VV;
      #pragma unroll
      for (int mf = 0; mf < 6; ++mf) {
        float4 bb = *(const float4*)&b_in[192 + mf * 16 + ldr4];
        const float* bp = (const float*)&bb;
        #pragma unroll
        for (int r = 0; r < 4; ++r) {
          int c = mf * 16 + ldr4 + r;
          val[(dt * 96 + c) * VALP + v] = f2b(acc[mf][r] + bp[r]);
        }
      }
    }
  }
  __syncthreads();

  // PV: D[u][col=dt*32+cm], col = wid*16+lrow (0..63)
  const unsigned short* attn = att + (size_t)(n * SS) * 1024;
  f32x4 y[3][2];
  #pragma unroll
  for (int s = 0; s < 3; ++s) { y[s][0] = fz(); y[s][1] = fz(); }

  {
    const int col = wid * 16 + lrow;
    const int dt = col >> 5, cm = col & 31;
    #pragma unroll
    for (int s = 0; s < 3; ++s) {
      bf16x8 b = ldbf8(&val[(dt * 96 + s * 32 + cm) * VALP + lk8]);
      #pragma unroll
      for (int mi = 0; mi < 2; ++mi) {
        bf16x8 a = ldbf8(&attn[(size_t)s * 1024 + (mi * 16 + lrow) * 32 + lk8]);
        y[s][mi] = MFMA16(a, b, y[s][mi]);
      }
    }
  }
  __syncthreads();

  // y -> yL[dt*25+u][c] (overlay val; 50*104*2 = 10400 B <= 15360 B)
  unsigned short* yL = val;
  {
    const int col = wid * 16 + lrow;
    const int dt = col >> 5, cm = col & 31;
    #pragma unroll
    for (int s = 0; s < 3; ++s) {
      const int c = s * 32 + cm;
      #pragma unroll
      for (int mi = 0; mi < 2; ++mi)
        #pragma unroll
        for (int r = 0; r < 4; ++r) {
          int u = mi * 16 + ldr4 + r;
          if (u < VV) yL[(dt * VV + u) * YLP + c] = f2b(y[s][mi][r]);
        }
    }
  }
  __syncthreads();

  // FF GEMM + BN + residual + leaky; wave handles col-frag wid
  {
    f32x4 acc[6];
    #pragma unroll
    for (int mf = 0; mf < 6; ++mf) acc[mf] = fz();
    #pragma unroll
    for (int ks = 0; ks < 3; ++ks) {
      bf16x8 b = ldbf8(&yL[(wid * 16 + lrow) * YLP + ks * 32 + lk8]);
      #pragma unroll
      for (int mf = 0; mf < 6; ++mf) {
        bf16x8 a = ldbf8(&wbff[(mf * 16 + lrow) * 96 + ks * 32 + lk8]);
        acc[mf] = MFMA16(a, b, acc[mf]);
      }
    }
    int i = wid * 16 + lrow;
    if (i < ROWS3) {
      int dt = i / VV, u = i - dt * VV;
      int t = t0 + dt;
      #pragma unroll
      for (int mf = 0; mf < 6; ++mf) {
        int o0 = mf * 16 + ldr4;
        ushort4 xr = *(const ushort4*)&xT[i * XTP + o0];
        float4 sc = *(const float4*)&scsh[o0];
        float4 sh = *(const float4*)&scsh[96 + o0];
        float zr[4];
        zr[0] = acc[mf][0] * sc.x + sh.x + b2f(xr.x);
        zr[1] = acc[mf][1] * sc.y + sh.y + b2f(xr.y);
        zr[2] = acc[mf][2] * sc.z + sh.z + b2f(xr.z);
        zr[3] = acc[mf][3] * sc.w + sh.w + b2f(xr.w);
        #pragma unroll
        for (int r = 0; r < 4; ++r) {
          float z = zr[r];
          z = (z >= 0.f) ? z : 0.1f * z;
          out[((size_t)(n * CC + o0 + r) * TT + t) * VV + u] = z;
        }
      }
    }
  }
}

// ---------------------------------------------------------------------------
extern "C" void kernel_launch(void* const* d_in, const int* in_sizes, int n_in,
                              void* d_out, int out_size, void* d_ws, size_t ws_size,
                              hipStream_t stream)
{
  const float* x     = (const float*)d_in[0];
  const float* p_att = (const float*)d_in[1];
  const float* b_att = (const float*)d_in[2];
  const float* w_in  = (const float*)d_in[3];
  const float* b_in  = (const float*)d_in[4];
  const float* w_ff  = (const float*)d_in[5];
  const float* b_ff  = (const float*)d_in[6];
  const float* gam   = (const float*)d_in[7];
  const float* bet   = (const float*)d_in[8];
  const float* mea   = (const float*)d_in[9];
  const float* var   = (const float*)d_in[10];
  float* out = (float*)d_out;

  char* ws = (char*)d_ws;
  unsigned short* wbin = (unsigned short*)ws;              // 288*96  @0
  unsigned short* wbff = wbin + 288 * 96;                  // 96*96   @55296
  unsigned short* attw = wbff + 96 * 96;                   // 192*1024 @73728
  float* scsh  = (float*)(ws + 466944);                    // 192 f32
  float* partG = (float*)(ws + 467712);                    // 192*32*625 f32

  k0<<<108, 256, 0, stream>>>(w_in, w_ff, b_ff, gam, bet, mea, var,
                              wbin, wbff, scsh);
  k1<<<NN * NTB, 256, 0, stream>>>(x, wbin, b_in, partG);
  k2<<<NN * SS, 256, 0, stream>>>(partG, p_att, b_att, attw);
  k3<<<NN * NTB3, 256, 0, stream>>>(x, wbin, wbff, b_in, scsh, attw, out);
}

// Round 5
// 127.773 us; speedup vs baseline: 1.3216x; 1.3216x over previous
//
#include <hip/hip_runtime.h>
#include <cmath>

#define NN 64
#define CC 96
#define TT 128
#define VV 25
#define SS 3
#define TB 4
#define NTB (TT/TB)          /* 32 */
#define ROWS (TB*VV)         /* 100 */
#define XTROWS 112

#define XTP 104              /* xT row pad (bf16 elems), 208B rows */
#define XFP 104              /* xf [c][i] staging pitch */
#define QKP 200              /* qk row pad, 400B rows */
#define VALP 40              /* val row pad, 80B rows */
#define YLP 104              /* y row pad, 208B rows */

typedef __attribute__((ext_vector_type(8))) __bf16 bf16x8;
typedef __attribute__((ext_vector_type(4))) float f32x4;

#define MFMA16(a,b,c) __builtin_amdgcn_mfma_f32_16x16x32_bf16((a),(b),(c),0,0,0)

__constant__ int JP[25] = {0,0,1,1,2,2,2,3,4,4,4,5,6,6,7,7,8,8,9,9,0,3,3,5,5};
__constant__ int JB[25] = {4,4,4,4,0,0,0,0,1,1,1,1,2,2,2,2,3,3,3,3,4,0,0,1,1};

__device__ inline unsigned short f2b(float f) {
  unsigned int u = __float_as_uint(f);
  u += 0x7fffu + ((u >> 16) & 1u);
  return (unsigned short)(u >> 16);
}
__device__ inline float b2f(unsigned short h) {
  return __uint_as_float(((unsigned int)h) << 16);
}
__device__ inline bf16x8 ldbf8(const unsigned short* p) {
  union { uint4 u; bf16x8 b; } z;
  z.u = *(const uint4*)p;
  return z.b;
}
__device__ inline f32x4 fz() {
  f32x4 z; z[0] = 0.f; z[1] = 0.f; z[2] = 0.f; z[3] = 0.f; return z;
}

// ---------------------------------------------------------------------------
// k0: weights -> bf16 in ws; BN scale/shift precompute
// ---------------------------------------------------------------------------
__global__ __launch_bounds__(256) void k0(
    const float* __restrict__ w_in, const float* __restrict__ w_ff,
    const float* __restrict__ b_ff, const float* __restrict__ gam,
    const float* __restrict__ bet, const float* __restrict__ mea,
    const float* __restrict__ var,
    unsigned short* __restrict__ wbin, unsigned short* __restrict__ wbff,
    float* __restrict__ scsh)
{
  int i = blockIdx.x * 256 + threadIdx.x;
  if (i < 288 * 96) wbin[i] = f2b(w_in[i]);
  if (i < 96 * 96)  wbff[i] = f2b(w_ff[i]);
  if (i < 96) {
    float sc = gam[i] * rsqrtf(var[i] + 1e-5f);
    scsh[i]      = sc;
    scsh[96 + i] = (b_ff[i] - mea[i]) * sc + bet[i];
  }
}

// ---------------------------------------------------------------------------
// Staging: coalesced float4 global loads -> xf[c][i] bf16 (contiguous LDS
// writes), barrier, LDS transpose -> xT[i][c].  xf aliases a later-used
// buffer (dead after phase B).
// ---------------------------------------------------------------------------
__device__ inline void stageA(const float* __restrict__ xb,
                              unsigned short* __restrict__ xf, int tid)
{
  for (int e = tid; e < CC * (ROWS / 4); e += 256) {
    int i4 = e % (ROWS / 4), c = e / (ROWS / 4);
    float4 v = *(const float4*)&xb[(size_t)c * (TT * VV) + i4 * 4];
    ushort4 h;
    h.x = f2b(v.x); h.y = f2b(v.y); h.z = f2b(v.z); h.w = f2b(v.w);
    *(ushort4*)&xf[c * XFP + i4 * 4] = h;
  }
}
__device__ inline void stageB(const unsigned short* __restrict__ xf,
                              unsigned short* __restrict__ xT, int tid)
{
  for (int e = tid; e < ROWS * (CC / 4); e += 256) {
    int i = e % ROWS, c4 = e / ROWS;
    ushort4 h;
    h.x = xf[(c4 * 4 + 0) * XFP + i];
    h.y = xf[(c4 * 4 + 1) * XFP + i];
    h.z = xf[(c4 * 4 + 2) * XFP + i];
    h.w = xf[(c4 * 4 + 3) * XFP + i];
    *(ushort4*)&xT[i * XTP + c4 * 4] = h;
  }
}

// ---------------------------------------------------------------------------
// k1: per (n, tb): QK GEMM (MFMA) -> Gram partials
// ---------------------------------------------------------------------------
__global__ __launch_bounds__(256, 2) void k1(
    const float* __restrict__ x, const unsigned short* __restrict__ wbin,
    const float* __restrict__ b_in, float* __restrict__ partG)
{
  __shared__ __align__(16) unsigned short xT[XTROWS * XTP];   // 23296 B
  __shared__ __align__(16) unsigned short qk[XTROWS * QKP];   // 44800 B; xf alias
  __shared__ float bL[192];
  unsigned short* xf = qk;   // 96*104 = 9984 ushorts <= qk size

  const int tid  = threadIdx.x;
  const int wid  = tid >> 6, lane = tid & 63;
  const int lrow = lane & 15;
  const int lk8  = (lane >> 4) << 3;
  const int ldr4 = (lane >> 4) << 2;
  const int tb = blockIdx.x & (NTB - 1);
  const int n  = blockIdx.x >> 5;
  const int t0 = tb * TB;

  const float* xb = x + (size_t)n * CC * TT * VV + (size_t)t0 * VV;
  stageA(xb, xf, tid);
  if (tid < 192) bL[tid] = b_in[tid];
  __syncthreads();
  stageB(xf, xT, tid);
  __syncthreads();

  // QK GEMM: D[o=0..191][col=0..111] ; wave handles mf = 3*wid..3*wid+2
  f32x4 acc[3][7];
  #pragma unroll
  for (int i = 0; i < 3; ++i)
    #pragma unroll
    for (int nf = 0; nf < 7; ++nf) acc[i][nf] = fz();

  #pragma unroll
  for (int ks = 0; ks < 3; ++ks) {
    bf16x8 a[3];
    #pragma unroll
    for (int i = 0; i < 3; ++i)
      a[i] = ldbf8(&wbin[((wid * 3 + i) * 16 + lrow) * 96 + ks * 32 + lk8]);
    #pragma unroll
    for (int nf = 0; nf < 7; ++nf) {
      bf16x8 b = ldbf8(&xT[(nf * 16 + lrow) * XTP + ks * 32 + lk8]);
      #pragma unroll
      for (int i = 0; i < 3; ++i)
        acc[i][nf] = MFMA16(a[i], b, acc[i][nf]);
    }
  }
  // bias + bf16 + store to qk[col][o]  (xf dead: barrier above passed)
  #pragma unroll
  for (int i = 0; i < 3; ++i) {
    int ob = (wid * 3 + i) * 16 + ldr4;
    float4 bb = *(const float4*)&bL[ob];
    #pragma unroll
    for (int nf = 0; nf < 7; ++nf) {
      int col = nf * 16 + lrow;
      ushort4 h;
      h.x = f2b(acc[i][nf][0] + bb.x);
      h.y = f2b(acc[i][nf][1] + bb.y);
      h.z = f2b(acc[i][nf][2] + bb.z);
      h.w = f2b(acc[i][nf][3] + bb.w);
      *(ushort4*)&qk[col * QKP + ob] = h;
    }
  }
  __syncthreads();

  // Gram: waves 0..2, s = wid
  if (wid < 3) {
    const int s = wid;
    f32x4 g[2][2];
    g[0][0] = fz(); g[0][1] = fz(); g[1][0] = fz(); g[1][1] = fz();
    #pragma unroll
    for (int dt = 0; dt < TB; ++dt) {
      int r0 = dt * VV;
      bf16x8 a0 = ldbf8(&qk[(r0 + lrow) * QKP + s * 32 + lk8]);
      bf16x8 a1 = ldbf8(&qk[(r0 + 16 + lrow) * QKP + s * 32 + lk8]);
      bf16x8 b0 = ldbf8(&qk[(r0 + lrow) * QKP + 96 + s * 32 + lk8]);
      bf16x8 b1 = ldbf8(&qk[(r0 + 16 + lrow) * QKP + 96 + s * 32 + lk8]);
      g[0][0] = MFMA16(a0, b0, g[0][0]);
      g[0][1] = MFMA16(a0, b1, g[0][1]);
      g[1][0] = MFMA16(a1, b0, g[1][0]);
      g[1][1] = MFMA16(a1, b1, g[1][1]);
    }
    // partG layout: [tb][ns][625] so k2 reads are coalesced
    float* pg = partG + ((size_t)tb * (NN * SS) + (n * SS + s)) * (VV * VV);
    #pragma unroll
    for (int mi = 0; mi < 2; ++mi)
      #pragma unroll
      for (int ni = 0; ni < 2; ++ni)
        #pragma unroll
        for (int r = 0; r < 4; ++r) {
          int u = mi * 16 + ldr4 + r, v = ni * 16 + lrow;
          if (u < VV && v < VV) pg[u * VV + v] = g[mi][ni][r];
        }
  }
}

// ---------------------------------------------------------------------------
// k2: reduce partials, tanh + positional gathers -> att bf16 [ns][32][32]
// ---------------------------------------------------------------------------
__global__ __launch_bounds__(256) void k2(
    const float* __restrict__ partG, const float* __restrict__ p_att,
    const float* __restrict__ b_att, unsigned short* __restrict__ att)
{
  const int ns = blockIdx.x;
  for (int e = threadIdx.x; e < 1024; e += 256) {
    int u = e >> 5, v = e & 31;
    float a = 0.f;
    if (u < VV && v < VV) {
      float g = 0.f;
      #pragma unroll 4
      for (int tb = 0; tb < NTB; ++tb)
        g += partG[((size_t)tb * (NN * SS) + ns) * (VV * VV) + u * VV + v];
      a = tanhf(g * (1.0f / 4096.0f))
        + p_att[(size_t)ns * 100 + JP[u] * 10 + JP[v]]
        + b_att[(size_t)ns * 25  + JB[u] * 5  + JB[v]];
    }
    att[(size_t)ns * 1024 + e] = f2b(a);
  }
}

// ---------------------------------------------------------------------------
// k3: per (n, tb): VAL GEMM -> PV -> FF GEMM -> BN + residual + leaky
// LDS = 23296 + 30720 = 54016 B -> 3 blocks/CU
// ---------------------------------------------------------------------------
__global__ __launch_bounds__(256, 2) void k3(
    const float* __restrict__ x, const unsigned short* __restrict__ wbin,
    const unsigned short* __restrict__ wbff,
    const float* __restrict__ b_in, const float* __restrict__ scsh,
    const unsigned short* __restrict__ att, float* __restrict__ out)
{
  __shared__ __align__(16) unsigned short xT[XTROWS * XTP];   // 23296 B
  __shared__ __align__(16) unsigned short val[384 * VALP];    // 30720 B; xf/yL alias
  unsigned short* xf = val;   // 9984 ushorts <= 15360

  const int tid  = threadIdx.x;
  const int wid  = tid >> 6, lane = tid & 63;
  const int lrow = lane & 15;
  const int lk8  = (lane >> 4) << 3;
  const int ldr4 = (lane >> 4) << 2;
  const int tb = blockIdx.x & (NTB - 1);
  const int n  = blockIdx.x >> 5;
  const int t0 = tb * TB;

  const float* xb = x + (size_t)n * CC * TT * VV + (size_t)t0 * VV;
  stageA(xb, xf, tid);
  __syncthreads();
  stageB(xf, xT, tid);
  __syncthreads();
  // zero val K-pad cols 24..31 (xf now dead; col 24 rewritten by VAL later)
  {
    uint4 z; z.x = 0u; z.y = 0u; z.z = 0u; z.w = 0u;
    for (int e = tid; e < 384; e += 256)
      *(uint4*)&val[e * VALP + 24] = z;
  }
  __syncthreads();

  // VAL GEMM: D[c=0..95][col=0..111]; wave handles nf = 2*wid .. min(+1,6)
  for (int nf = wid * 2; nf < 7 && nf < wid * 2 + 2; ++nf) {
    f32x4 acc[6];
    #pragma unroll
    for (int mf = 0; mf < 6; ++mf) acc[mf] = fz();
    #pragma unroll
    for (int ks = 0; ks < 3; ++ks) {
      bf16x8 b = ldbf8(&xT[(nf * 16 + lrow) * XTP + ks * 32 + lk8]);
      #pragma unroll
      for (int mf = 0; mf < 6; ++mf) {
        bf16x8 a = ldbf8(&wbin[(192 + mf * 16 + lrow) * 96 + ks * 32 + lk8]);
        acc[mf] = MFMA16(a, b, acc[mf]);
      }
    }
    int col = nf * 16 + lrow;
    if (col < ROWS) {
      int dt = col / VV, v = col - dt * VV;
      #pragma unroll
      for (int mf = 0; mf < 6; ++mf) {
        float4 bb = *(const float4*)&b_in[192 + mf * 16 + ldr4];
        const float* bp = (const float*)&bb;
        #pragma unroll
        for (int r = 0; r < 4; ++r) {
          int c = mf * 16 + ldr4 + r;
          val[(dt * 96 + c) * VALP + v] = f2b(acc[mf][r] + bp[r]);
        }
      }
    }
  }
  __syncthreads();

  // PV: per s: D[u][col=dt*32+cm]; att frags straight from global (L2-hot)
  const unsigned short* attn = att + (size_t)(n * SS) * 1024;
  f32x4 y[3][2][2];
  #pragma unroll
  for (int s = 0; s < 3; ++s)
    #pragma unroll
    for (int mi = 0; mi < 2; ++mi)
      #pragma unroll
      for (int ci = 0; ci < 2; ++ci) y[s][mi][ci] = fz();

  #pragma unroll
  for (int s = 0; s < 3; ++s) {
    bf16x8 b[2];
    #pragma unroll
    for (int ci = 0; ci < 2; ++ci) {
      int col = (wid * 2 + ci) * 16 + lrow;   // 0..127
      int dt = col >> 5, cm = col & 31;
      b[ci] = ldbf8(&val[(dt * 96 + s * 32 + cm) * VALP + lk8]);
    }
    #pragma unroll
    for (int mi = 0; mi < 2; ++mi) {
      bf16x8 a = ldbf8(&attn[(size_t)s * 1024 + (mi * 16 + lrow) * 32 + lk8]);
      #pragma unroll
      for (int ci = 0; ci < 2; ++ci)
        y[s][mi][ci] = MFMA16(a, b[ci], y[s][mi][ci]);
    }
  }
  __syncthreads();

  // y -> yL[dt*25+u][c] (overlay val)
  unsigned short* yL = val;
  #pragma unroll
  for (int s = 0; s < 3; ++s)
    #pragma unroll
    for (int mi = 0; mi < 2; ++mi)
      #pragma unroll
      for (int ci = 0; ci < 2; ++ci) {
        int col = (wid * 2 + ci) * 16 + lrow;
        int dt = col >> 5, cm = col & 31;
        int c = s * 32 + cm;
        #pragma unroll
        for (int r = 0; r < 4; ++r) {
          int u = mi * 16 + ldr4 + r;
          if (u < VV) yL[(dt * VV + u) * YLP + c] = f2b(y[s][mi][ci][r]);
        }
      }
  __syncthreads();

  // FF GEMM + BN + residual + leaky epilogue
  for (int nf = wid * 2; nf < 7 && nf < wid * 2 + 2; ++nf) {
    f32x4 acc[6];
    #pragma unroll
    for (int mf = 0; mf < 6; ++mf) acc[mf] = fz();
    #pragma unroll
    for (int ks = 0; ks < 3; ++ks) {
      bf16x8 b = ldbf8(&yL[(nf * 16 + lrow) * YLP + ks * 32 + lk8]);
      #pragma unroll
      for (int mf = 0; mf < 6; ++mf) {
        bf16x8 a = ldbf8(&wbff[(mf * 16 + lrow) * 96 + ks * 32 + lk8]);
        acc[mf] = MFMA16(a, b, acc[mf]);
      }
    }
    int i = nf * 16 + lrow;
    if (i < ROWS) {
      int dt = i / VV, u = i - dt * VV;
      int t = t0 + dt;
      #pragma unroll
      for (int mf = 0; mf < 6; ++mf) {
        int o0 = mf * 16 + ldr4;
        ushort4 xr = *(const ushort4*)&xT[i * XTP + o0];
        float4 sc = *(const float4*)&scsh[o0];
        float4 sh = *(const float4*)&scsh[96 + o0];
        float zr[4];
        zr[0] = acc[mf][0] * sc.x + sh.x + b2f(xr.x);
        zr[1] = acc[mf][1] * sc.y + sh.y + b2f(xr.y);
        zr[2] = acc[mf][2] * sc.z + sh.z + b2f(xr.z);
        zr[3] = acc[mf][3] * sc.w + sh.w + b2f(xr.w);
        #pragma unroll
        for (int r = 0; r < 4; ++r) {
          float z = zr[r];
          z = (z >= 0.f) ? z : 0.1f * z;
          out[((size_t)(n * CC + o0 + r) * TT + t) * VV + u] = z;
        }
      }
    }
  }
}

// ---------------------------------------------------------------------------
extern "C" void kernel_launch(void* const* d_in, const int* in_sizes, int n_in,
                              void* d_out, int out_size, void* d_ws, size_t ws_size,
                              hipStream_t stream)
{
  const float* x     = (const float*)d_in[0];
  const float* p_att = (const float*)d_in[1];
  const float* b_att = (const float*)d_in[2];
  const float* w_in  = (const float*)d_in[3];
  const float* b_in  = (const float*)d_in[4];
  const float* w_ff  = (const float*)d_in[5];
  const float* b_ff  = (const float*)d_in[6];
  const float* gam   = (const float*)d_in[7];
  const float* bet   = (const float*)d_in[8];
  const float* mea   = (const float*)d_in[9];
  const float* var   = (const float*)d_in[10];
  float* out = (float*)d_out;

  char* ws = (char*)d_ws;
  unsigned short* wbin = (unsigned short*)ws;              // 288*96  @0
  unsigned short* wbff = wbin + 288 * 96;                  // 96*96
  unsigned short* attw = wbff + 96 * 96;                   // 192*1024
  float* scsh  = (float*)(ws + 466944);                    // 192 f32
  float* partG = (float*)(ws + 467712);                    // 32*192*625 f32

  k0<<<108, 256, 0, stream>>>(w_in, w_ff, b_ff, gam, bet, mea, var,
                              wbin, wbff, scsh);
  k1<<<NN * NTB, 256, 0, stream>>>(x, wbin, b_in, partG);
  k2<<<NN * SS, 256, 0, stream>>>(partG, p_att, b_att, attw);
  k3<<<NN * NTB, 256, 0, stream>>>(x, wbin, wbff, b_in, scsh, attw, out);
}